// Round 13
// baseline (3557.543 us; speedup 1.0000x reference)
//
#include <hip/hip_runtime.h>
#include <math.h>

// Problem constants (match reference setup_inputs)
#define NN 50000
#define EE 150000
#define LL 15

typedef __attribute__((ext_vector_type(8))) short short8;
typedef __attribute__((ext_vector_type(4))) float f32x4;
typedef __attribute__((ext_vector_type(2))) float f32x2;

// Paired exact-GELU via A&S 7.1.25 erf (|err| <= 2.5e-5 — ~100x below bf16 quantum).
// f32x2 arithmetic selects v_pk_fma_f32/v_pk_mul_f32 on gfx950 (dual fp32/instr).
static __device__ __forceinline__ void gelu2(float x0, float x1, float& o0, float& o1) {
    f32x2 x = {x0, x1};
    f32x2 ax = {fabsf(x0), fabsf(x1)};
    f32x2 z = ax * 0.70710678118654752440f;
    float t0 = __builtin_amdgcn_rcpf(fmaf(0.47047f, z[0], 1.0f));
    float t1 = __builtin_amdgcn_rcpf(fmaf(0.47047f, z[1], 1.0f));
    f32x2 t = {t0, t1};
    f32x2 poly = t * 0.7478556f + (f32x2)(-0.0958798f);
    poly = poly * t + (f32x2)0.3480242f;
    poly = poly * t;
    f32x2 nz2 = -z * z;
    f32x2 ex = {__expf(nz2[0]), __expf(nz2[1])};
    f32x2 erf = (f32x2)1.0f - poly * ex;
    float e0 = copysignf(erf[0], x0);
    float e1 = copysignf(erf[1], x1);
    o0 = 0.5f * x0 * (1.0f + e0);
    o1 = 0.5f * x1 * (1.0f + e1);
}

static __device__ __forceinline__ unsigned short bf16_of(float f) {
    union { float f; unsigned u; } v;
    v.f = f;
    unsigned r = (v.u + 0x7fffu + ((v.u >> 16) & 1u)) >> 16;  // RNE
    return (unsigned short)r;
}

static __device__ __forceinline__ float f_of_bf16(unsigned short u) {
    union { unsigned u; float f; } v;
    v.u = ((unsigned)u) << 16;
    return v.f;
}

// ---------------- weight transpose+convert+pad:
// in [C][K][N] fp32 -> out [C][Npad][Kpad] bf16 (zero-padded)
__global__ __launch_bounds__(256) void wt_t_kernel(const float* __restrict__ in,
                                                   unsigned short* __restrict__ out,
                                                   int K, int N, int Kpad, int Npad, int total) {
    int i = blockIdx.x * 256 + threadIdx.x;
    if (i >= total) return;
    int k = i % Kpad;
    int r = i / Kpad;
    int n = r % Npad;
    int c = r / Npad;
    out[i] = (k < K && n < N) ? bf16_of(in[((size_t)c * K + k) * N + n]) : (unsigned short)0;
}

// ---------------- CSR build: histogram
__global__ __launch_bounds__(256) void hist_kernel(const int* __restrict__ senders,
                                                   const int* __restrict__ receivers,
                                                   int* __restrict__ cntR, int* __restrict__ cntS) {
    int i = blockIdx.x * 256 + threadIdx.x;
    if (i >= EE) return;
    atomicAdd(&cntR[receivers[i]], 1);
    atomicAdd(&cntS[senders[i]], 1);
}

// ---------------- CSR build: bucket allocation (order-free; wave scan + 1 atomic/wave)
__global__ __launch_bounds__(256) void alloc_kernel(const int* __restrict__ cntR,
                                                    const int* __restrict__ cntS,
                                                    int* __restrict__ offR, int* __restrict__ offS,
                                                    int* __restrict__ curR, int* __restrict__ curS,
                                                    int* __restrict__ ctr) {
    int i = blockIdx.x * 256 + threadIdx.x;
    int lane = threadIdx.x & 63;
    int cR = (i < NN) ? cntR[i] : 0;
    int cS = (i < NN) ? cntS[i] : 0;
    int sR = cR, sS = cS;
#pragma unroll
    for (int d = 1; d < 64; d <<= 1) {
        int tR = __shfl_up(sR, d, 64);
        int tS = __shfl_up(sS, d, 64);
        if (lane >= d) { sR += tR; sS += tS; }
    }
    int baseR = 0, baseS = 0;
    if (lane == 63) {
        baseR = atomicAdd(&ctr[0], sR);
        baseS = atomicAdd(&ctr[1], sS);
    }
    baseR = __shfl(baseR, 63, 64);
    baseS = __shfl(baseS, 63, 64);
    if (i < NN) {
        int oR = baseR + sR - cR;
        offR[i] = oR; curR[i] = oR;
        int oS = baseS + sS - cS;
        offS[i] = oS; curS[i] = oS;
    }
}

// ---------------- CSR build: fill — receiver-sorted edge permutation.
__global__ __launch_bounds__(256) void fill_kernel(const int* __restrict__ senders,
                                                   const int* __restrict__ receivers,
                                                   int* __restrict__ curR, int* __restrict__ curS,
                                                   int* __restrict__ iperm,
                                                   int* __restrict__ sendP, int* __restrict__ recvP,
                                                   int* __restrict__ csrS) {
    int i = blockIdx.x * 256 + threadIdx.x;
    if (i >= EE) return;
    int snd = senders[i], rcv = receivers[i];
    int pr = atomicAdd(&curR[rcv], 1);
    iperm[pr] = i;
    sendP[pr] = snd;
    recvP[pr] = rcv;
    int ps = atomicAdd(&curS[snd], 1);
    csrS[ps] = pr;
}

// ======== shared MFMA helpers ========
template <int MT>
static __device__ __forceinline__ void mlp_from_h(const unsigned short* hb,
                                                  const unsigned short* __restrict__ Wt,
                                                  f32x4 acc[][8], int m, int q) {
#pragma unroll
    for (int c = 0; c < 4; ++c) {
        short8 af[MT];
#pragma unroll
        for (int mt = 0; mt < MT; ++mt)
            af[mt] = *(const short8*)(hb + (mt * 16 + m) * 136 + c * 32 + q * 8);
#pragma unroll
        for (int nt = 0; nt < 8; ++nt) {
            short8 bf = *(const short8*)(Wt + ((size_t)(nt * 16 + m)) * 128 + c * 32 + q * 8);
#pragma unroll
            for (int mt = 0; mt < MT; ++mt)
                acc[mt][nt] = __builtin_amdgcn_mfma_f32_16x16x32_bf16(af[mt], bf, acc[mt][nt], 0, 0, 0);
        }
    }
}

template <int MT>
static __device__ __forceinline__ void gelu_to_h(f32x4 acc[][8], const float* __restrict__ b,
                                                 unsigned short* hb, int m, int q) {
#pragma unroll
    for (int nt = 0; nt < 8; ++nt) {
        float bv = b[nt * 16 + m];
#pragma unroll
        for (int mt = 0; mt < MT; ++mt) {
#pragma unroll
            for (int r = 0; r < 4; r += 2) {
                float g0, g1;
                gelu2(acc[mt][nt][r] + bv, acc[mt][nt][r + 1] + bv, g0, g1);
                hb[(mt * 16 + q * 4 + r) * 136 + nt * 16 + m] = bf16_of(g0);
                hb[(mt * 16 + q * 4 + r + 1) * 136 + nt * 16 + m] = bf16_of(g1);
            }
            acc[mt][nt] = (f32x4)0.f;
        }
    }
}

// ================= MFMA edge block: 192 edges/block, 4 waves x 48 rows (3 m-tiles)
// (256,4) pins VGPR budget at 128 (R11/R12: natural 120-124, no spills).
template <bool WRITE_EL>
__global__ __launch_bounds__(256, 4) void edge_mfma_kernel(
    const unsigned short* __restrict__ xb, float* __restrict__ el,
    unsigned short* __restrict__ enew,
    const int* __restrict__ sendP, const int* __restrict__ recvP,
    const unsigned short* __restrict__ W1t, const float* __restrict__ b1,
    const unsigned short* __restrict__ W2t, const float* __restrict__ b2,
    const unsigned short* __restrict__ W3t, const float* __restrict__ b3,
    const float* __restrict__ g, const float* __restrict__ beta) {
    __shared__ __align__(16) unsigned short h[4][48][136];  // 52.2 KB
    int t = threadIdx.x;
    int w = t >> 6;
    int l = t & 63;
    int m = l & 15;
    int q = l >> 4;
    int rbase = blockIdx.x * 192 + w * 48;

    int arow[3], as[3], ar[3];
#pragma unroll
    for (int mt = 0; mt < 3; ++mt) {
        int rw = rbase + mt * 16 + m;
        if (rw >= EE) rw = EE - 1;
        arow[mt] = rw;
        as[mt] = sendP[rw];
        ar[mt] = recvP[rw];
    }

    f32x4 acc[3][8];
#pragma unroll
    for (int mt = 0; mt < 3; ++mt)
#pragma unroll
        for (int nt = 0; nt < 8; ++nt) acc[mt][nt] = (f32x4)0.f;

    // ---- MLP1: K=384 (12 chunks): 0..3 x[sender], 4..7 x[receiver], 8..11 e (fp32->bf16)
#pragma unroll
    for (int c = 0; c < 12; ++c) {
        short8 af[3];
#pragma unroll
        for (int mt = 0; mt < 3; ++mt) {
            if (c < 4) {
                af[mt] = *(const short8*)(xb + (size_t)as[mt] * 128 + c * 32 + q * 8);
            } else if (c < 8) {
                af[mt] = *(const short8*)(xb + (size_t)ar[mt] * 128 + (c - 4) * 32 + q * 8);
            } else {
                const float* fp = el + (size_t)arow[mt] * 128 + (c - 8) * 32 + q * 8;
                float4 f0 = *(const float4*)fp;
                float4 f1 = *(const float4*)(fp + 4);
                short8 a;
                a[0] = (short)bf16_of(f0.x); a[1] = (short)bf16_of(f0.y);
                a[2] = (short)bf16_of(f0.z); a[3] = (short)bf16_of(f0.w);
                a[4] = (short)bf16_of(f1.x); a[5] = (short)bf16_of(f1.y);
                a[6] = (short)bf16_of(f1.z); a[7] = (short)bf16_of(f1.w);
                af[mt] = a;
            }
        }
#pragma unroll
        for (int nt = 0; nt < 8; ++nt) {
            short8 bf = *(const short8*)(W1t + ((size_t)(nt * 16 + m)) * 384 + c * 32 + q * 8);
#pragma unroll
            for (int mt = 0; mt < 3; ++mt)
                acc[mt][nt] = __builtin_amdgcn_mfma_f32_16x16x32_bf16(af[mt], bf, acc[mt][nt], 0, 0, 0);
        }
    }
    gelu_to_h<3>(acc, b1, &h[w][0][0], m, q);
    mlp_from_h<3>(&h[w][0][0], W2t, acc, m, q);
    gelu_to_h<3>(acc, b2, &h[w][0][0], m, q);
    mlp_from_h<3>(&h[w][0][0], W3t, acc, m, q);

    // ---- epilogue: bias, LN over 128, residual into el (compile-time-skipped last layer)
    float gv[8], btv[8];
#pragma unroll
    for (int nt = 0; nt < 8; ++nt) { gv[nt] = g[nt * 16 + m]; btv[nt] = beta[nt * 16 + m]; }
#pragma unroll
    for (int mt = 0; mt < 3; ++mt) {
        float s[4] = {0.f, 0.f, 0.f, 0.f}, ss[4] = {0.f, 0.f, 0.f, 0.f};
#pragma unroll
        for (int nt = 0; nt < 8; ++nt) {
            float bv = b3[nt * 16 + m];
#pragma unroll
            for (int r = 0; r < 4; ++r) {
                float v = acc[mt][nt][r] + bv;
                acc[mt][nt][r] = v;
                s[r] += v;
                ss[r] += v * v;
            }
        }
#pragma unroll
        for (int r = 0; r < 4; ++r) {
#pragma unroll
            for (int msk = 1; msk < 16; msk <<= 1) {
                s[r] += __shfl_xor(s[r], msk, 64);
                ss[r] += __shfl_xor(ss[r], msk, 64);
            }
        }
#pragma unroll
        for (int r = 0; r < 4; ++r) {
            int row = rbase + mt * 16 + q * 4 + r;
            if (row < EE) {
                float mean = s[r] * (1.0f / 128.0f);
                float var = ss[r] * (1.0f / 128.0f) - mean * mean;
                float rstd = rsqrtf(var + 1e-5f);
#pragma unroll
                for (int nt = 0; nt < 8; ++nt) {
                    int col = nt * 16 + m;
                    float v = (acc[mt][nt][r] - mean) * rstd * gv[nt] + btv[nt];
                    size_t off = (size_t)row * 128 + col;
                    if (WRITE_EL) el[off] = el[off] + v;
                    enew[off] = bf16_of(v);
                }
            }
        }
    }
}

// ================= MFMA node block: 64 nodes/block, 4 waves x 16 rows (1 m-tile)
// [R13] mt=1: grid 391->782 blocks, LDS 34.8->17.4 KB, acc 64->32 VGPR — fixes the
// 1.5-blocks/CU grid starvation (half the CUs idled during node dispatches).
template <bool WRITE_XL>
__global__ __launch_bounds__(256) void node_mfma_kernel(
    float* __restrict__ xl, unsigned short* __restrict__ xb,
    const unsigned short* __restrict__ enew,
    const int* __restrict__ offR, const int* __restrict__ cntR,
    const int* __restrict__ offS, const int* __restrict__ cntS, const int* __restrict__ csrS,
    const unsigned short* __restrict__ W1t, const float* __restrict__ b1,
    const unsigned short* __restrict__ W2t, const float* __restrict__ b2,
    const unsigned short* __restrict__ W3t, const float* __restrict__ b3,
    const float* __restrict__ g, const float* __restrict__ beta) {
    __shared__ __align__(16) unsigned short h[4][16][136];  // 17.4 KB
    int t = threadIdx.x;
    int w = t >> 6;
    int l = t & 63;
    int m = l & 15;
    int q = l >> 4;
    int rbase = blockIdx.x * 64 + w * 16;

    // ---- aggregation prologue (no atomics; R-half contiguous, unroll-2)
    float aggv[1][16];
#pragma unroll
    for (int j = 0; j < 16; ++j) aggv[0][j] = 0.f;
    {
        int rw = rbase + m;
        if (rw < NN) {
            // receiver half (cols 0..63), contiguous rows
            {
                int b0 = offR[rw], bn = b0 + cntR[rw];
                int p = b0;
                for (; p + 2 <= bn; p += 2) {
                    const unsigned short* bp0 = enew + (size_t)p * 128;
                    short8 a0 = *(const short8*)(bp0 + q * 8);
                    short8 a1 = *(const short8*)(bp0 + 32 + q * 8);
                    short8 c0 = *(const short8*)(bp0 + 128 + q * 8);
                    short8 c1 = *(const short8*)(bp0 + 128 + 32 + q * 8);
#pragma unroll
                    for (int j = 0; j < 8; ++j) {
                        aggv[0][j] += f_of_bf16((unsigned short)a0[j]) + f_of_bf16((unsigned short)c0[j]);
                        aggv[0][8 + j] += f_of_bf16((unsigned short)a1[j]) + f_of_bf16((unsigned short)c1[j]);
                    }
                }
                if (p < bn) {
                    const unsigned short* bp0 = enew + (size_t)p * 128;
                    short8 a0 = *(const short8*)(bp0 + q * 8);
                    short8 a1 = *(const short8*)(bp0 + 32 + q * 8);
#pragma unroll
                    for (int j = 0; j < 8; ++j) {
                        aggv[0][j] += f_of_bf16((unsigned short)a0[j]);
                        aggv[0][8 + j] += f_of_bf16((unsigned short)a1[j]);
                    }
                }
            }
            // sender half (cols 64..127), gather via csrS (permuted ids)
            {
                int b0 = offS[rw], bn = b0 + cntS[rw];
                int p = b0;
                for (; p + 2 <= bn; p += 2) {
                    int e0 = csrS[p], e1 = csrS[p + 1];
                    const unsigned short* bp0 = enew + (size_t)e0 * 128 + 64;
                    const unsigned short* bp1 = enew + (size_t)e1 * 128 + 64;
                    short8 a0 = *(const short8*)(bp0 + q * 8);
                    short8 a1 = *(const short8*)(bp0 + 32 + q * 8);
                    short8 c0 = *(const short8*)(bp1 + q * 8);
                    short8 c1 = *(const short8*)(bp1 + 32 + q * 8);
#pragma unroll
                    for (int j = 0; j < 8; ++j) {
                        aggv[0][j] += f_of_bf16((unsigned short)a0[j]) + f_of_bf16((unsigned short)c0[j]);
                        aggv[0][8 + j] += f_of_bf16((unsigned short)a1[j]) + f_of_bf16((unsigned short)c1[j]);
                    }
                }
                if (p < bn) {
                    int e0 = csrS[p];
                    const unsigned short* bp0 = enew + (size_t)e0 * 128 + 64;
                    short8 a0 = *(const short8*)(bp0 + q * 8);
                    short8 a1 = *(const short8*)(bp0 + 32 + q * 8);
#pragma unroll
                    for (int j = 0; j < 8; ++j) {
                        aggv[0][j] += f_of_bf16((unsigned short)a0[j]);
                        aggv[0][8 + j] += f_of_bf16((unsigned short)a1[j]);
                    }
                }
            }
        }
    }

    int arow = rbase + m;
    if (arow >= NN) arow = NN - 1;

    f32x4 acc[1][8];
#pragma unroll
    for (int nt = 0; nt < 8; ++nt) acc[0][nt] = (f32x4)0.f;

    // ---- MLP1: K=192 (6 chunks): 0..3 xb, 4..5 agg (registers)
#pragma unroll
    for (int c = 0; c < 6; ++c) {
        short8 af;
        if (c < 4) {
            af = *(const short8*)(xb + (size_t)arow * 128 + c * 32 + q * 8);
        } else {
            short8 a;
#pragma unroll
            for (int j = 0; j < 8; ++j)
                a[j] = (short)bf16_of(aggv[0][(c - 4) * 8 + j]);
            af = a;
        }
#pragma unroll
        for (int nt = 0; nt < 8; ++nt) {
            short8 bf = *(const short8*)(W1t + ((size_t)(nt * 16 + m)) * 192 + c * 32 + q * 8);
            acc[0][nt] = __builtin_amdgcn_mfma_f32_16x16x32_bf16(af, bf, acc[0][nt], 0, 0, 0);
        }
    }
    gelu_to_h<1>(acc, b1, &h[w][0][0], m, q);
    mlp_from_h<1>(&h[w][0][0], W2t, acc, m, q);
    gelu_to_h<1>(acc, b2, &h[w][0][0], m, q);
    mlp_from_h<1>(&h[w][0][0], W3t, acc, m, q);

    // ---- epilogue: LN, residual into xl (compile-time-skipped last layer), xb mirror
    float gv[8], btv[8];
#pragma unroll
    for (int nt = 0; nt < 8; ++nt) { gv[nt] = g[nt * 16 + m]; btv[nt] = beta[nt * 16 + m]; }
    {
        float s[4] = {0.f, 0.f, 0.f, 0.f}, ss[4] = {0.f, 0.f, 0.f, 0.f};
#pragma unroll
        for (int nt = 0; nt < 8; ++nt) {
            float bv = b3[nt * 16 + m];
#pragma unroll
            for (int r = 0; r < 4; ++r) {
                float v = acc[0][nt][r] + bv;
                acc[0][nt][r] = v;
                s[r] += v;
                ss[r] += v * v;
            }
        }
#pragma unroll
        for (int r = 0; r < 4; ++r) {
#pragma unroll
            for (int msk = 1; msk < 16; msk <<= 1) {
                s[r] += __shfl_xor(s[r], msk, 64);
                ss[r] += __shfl_xor(ss[r], msk, 64);
            }
        }
#pragma unroll
        for (int r = 0; r < 4; ++r) {
            int row = rbase + q * 4 + r;
            if (row < NN) {
                float mean = s[r] * (1.0f / 128.0f);
                float var = ss[r] * (1.0f / 128.0f) - mean * mean;
                float rstd = rsqrtf(var + 1e-5f);
#pragma unroll
                for (int nt = 0; nt < 8; ++nt) {
                    int col = nt * 16 + m;
                    float v = (acc[0][nt][r] - mean) * rstd * gv[nt] + btv[nt];
                    size_t off = (size_t)row * 128 + col;
                    float res = xl[off] + v;
                    if (WRITE_XL) xl[off] = res;
                    xb[off] = bf16_of(res);
                }
            }
        }
    }
}

// ================= MFMA encoder: [rows,16] -> MLP(16->128->128->128) -> LN
__global__ __launch_bounds__(256) void enc_mfma_kernel(
    const float* __restrict__ in, const int* __restrict__ gather,
    const unsigned short* __restrict__ W1p, const float* __restrict__ b1,
    const unsigned short* __restrict__ W2t, const float* __restrict__ b2,
    const unsigned short* __restrict__ W3t, const float* __restrict__ b3,
    const float* __restrict__ g, const float* __restrict__ beta,
    float* __restrict__ outF, unsigned short* __restrict__ outB, int nrows) {
    __shared__ __align__(16) unsigned short h[4][32][136];
    int t = threadIdx.x;
    int w = t >> 6;
    int l = t & 63;
    int m = l & 15;
    int q = l >> 4;
    int rbase = blockIdx.x * 128 + w * 32;

    int arow[2];
#pragma unroll
    for (int mt = 0; mt < 2; ++mt) {
        int rw = rbase + mt * 16 + m;
        rw = (rw < nrows) ? rw : (nrows - 1);
        arow[mt] = gather ? gather[rw] : rw;
    }

    f32x4 acc[2][8];
#pragma unroll
    for (int mt = 0; mt < 2; ++mt)
#pragma unroll
        for (int nt = 0; nt < 8; ++nt) acc[mt][nt] = (f32x4)0.f;

    // ---- MLP1: single K=32 chunk (k>=16 zero)
    {
        short8 af[2];
#pragma unroll
        for (int mt = 0; mt < 2; ++mt) {
            short8 a = (short8)0;
            if (q < 2) {
                const float* fp = in + (size_t)arow[mt] * 16 + q * 8;
                float4 f0 = *(const float4*)fp;
                float4 f1 = *(const float4*)(fp + 4);
                a[0] = (short)bf16_of(f0.x); a[1] = (short)bf16_of(f0.y);
                a[2] = (short)bf16_of(f0.z); a[3] = (short)bf16_of(f0.w);
                a[4] = (short)bf16_of(f1.x); a[5] = (short)bf16_of(f1.y);
                a[6] = (short)bf16_of(f1.z); a[7] = (short)bf16_of(f1.w);
            }
            af[mt] = a;
        }
#pragma unroll
        for (int nt = 0; nt < 8; ++nt) {
            short8 bf = *(const short8*)(W1p + ((size_t)(nt * 16 + m)) * 32 + q * 8);
#pragma unroll
            for (int mt = 0; mt < 2; ++mt)
                acc[mt][nt] = __builtin_amdgcn_mfma_f32_16x16x32_bf16(af[mt], bf, acc[mt][nt], 0, 0, 0);
        }
    }
    gelu_to_h<2>(acc, b1, &h[w][0][0], m, q);
    mlp_from_h<2>(&h[w][0][0], W2t, acc, m, q);
    gelu_to_h<2>(acc, b2, &h[w][0][0], m, q);
    mlp_from_h<2>(&h[w][0][0], W3t, acc, m, q);

    float gv[8], btv[8];
#pragma unroll
    for (int nt = 0; nt < 8; ++nt) { gv[nt] = g[nt * 16 + m]; btv[nt] = beta[nt * 16 + m]; }
#pragma unroll
    for (int mt = 0; mt < 2; ++mt) {
        float s[4] = {0.f, 0.f, 0.f, 0.f}, ss[4] = {0.f, 0.f, 0.f, 0.f};
#pragma unroll
        for (int nt = 0; nt < 8; ++nt) {
            float bv = b3[nt * 16 + m];
#pragma unroll
            for (int r = 0; r < 4; ++r) {
                float v = acc[mt][nt][r] + bv;
                acc[mt][nt][r] = v;
                s[r] += v;
                ss[r] += v * v;
            }
        }
#pragma unroll
        for (int r = 0; r < 4; ++r) {
#pragma unroll
            for (int msk = 1; msk < 16; msk <<= 1) {
                s[r] += __shfl_xor(s[r], msk, 64);
                ss[r] += __shfl_xor(ss[r], msk, 64);
            }
        }
#pragma unroll
        for (int r = 0; r < 4; ++r) {
            int row = rbase + mt * 16 + q * 4 + r;
            if (row < nrows) {
                float mean = s[r] * (1.0f / 128.0f);
                float var = ss[r] * (1.0f / 128.0f) - mean * mean;
                float rstd = rsqrtf(var + 1e-5f);
#pragma unroll
                for (int nt = 0; nt < 8; ++nt) {
                    int col = nt * 16 + m;
                    float v = (acc[mt][nt][r] - mean) * rstd * gv[nt] + btv[nt];
                    size_t off = (size_t)row * 128 + col;
                    outF[off] = v;
                    if (outB) outB[off] = bf16_of(v);
                }
            }
        }
    }
}

// ================= MFMA decoder: xb -> MLP(128->128->128->3)
__global__ __launch_bounds__(256) void dec_mfma_kernel(
    const unsigned short* __restrict__ xb,
    const unsigned short* __restrict__ W1t, const float* __restrict__ b1,
    const unsigned short* __restrict__ W2t, const float* __restrict__ b2,
    const unsigned short* __restrict__ W3p, const float* __restrict__ b3,
    float* __restrict__ out, int N_) {
    __shared__ __align__(16) unsigned short h[4][32][136];
    int t = threadIdx.x;
    int w = t >> 6;
    int l = t & 63;
    int m = l & 15;
    int q = l >> 4;
    int rbase = blockIdx.x * 128 + w * 32;

    int arow[2];
#pragma unroll
    for (int mt = 0; mt < 2; ++mt) {
        int rw = rbase + mt * 16 + m;
        arow[mt] = (rw < N_) ? rw : (N_ - 1);
    }

    f32x4 acc[2][8];
#pragma unroll
    for (int mt = 0; mt < 2; ++mt)
#pragma unroll
        for (int nt = 0; nt < 8; ++nt) acc[mt][nt] = (f32x4)0.f;

    // ---- MLP1: K=128 from xb
#pragma unroll
    for (int c = 0; c < 4; ++c) {
        short8 af[2];
#pragma unroll
        for (int mt = 0; mt < 2; ++mt)
            af[mt] = *(const short8*)(xb + (size_t)arow[mt] * 128 + c * 32 + q * 8);
#pragma unroll
        for (int nt = 0; nt < 8; ++nt) {
            short8 bf = *(const short8*)(W1t + ((size_t)(nt * 16 + m)) * 128 + c * 32 + q * 8);
#pragma unroll
            for (int mt = 0; mt < 2; ++mt)
                acc[mt][nt] = __builtin_amdgcn_mfma_f32_16x16x32_bf16(af[mt], bf, acc[mt][nt], 0, 0, 0);
        }
    }
    gelu_to_h<2>(acc, b1, &h[w][0][0], m, q);
    mlp_from_h<2>(&h[w][0][0], W2t, acc, m, q);
    gelu_to_h<2>(acc, b2, &h[w][0][0], m, q);

    // ---- final: 128 -> 3 (one padded n-tile)
    f32x4 a3[2];
    a3[0] = (f32x4)0.f;
    a3[1] = (f32x4)0.f;
#pragma unroll
    for (int c = 0; c < 4; ++c) {
        short8 bf = *(const short8*)(W3p + ((size_t)m) * 128 + c * 32 + q * 8);
#pragma unroll
        for (int mt = 0; mt < 2; ++mt) {
            short8 af = *(const short8*)(&h[w][0][0] + (mt * 16 + m) * 136 + c * 32 + q * 8);
            a3[mt] = __builtin_amdgcn_mfma_f32_16x16x32_bf16(af, bf, a3[mt], 0, 0, 0);
        }
    }
    if (m < 3) {
        float bv = b3[m];
#pragma unroll
        for (int mt = 0; mt < 2; ++mt) {
#pragma unroll
            for (int r = 0; r < 4; ++r) {
                int row = rbase + mt * 16 + q * 4 + r;
                if (row < N_) out[(size_t)row * 3 + m] = a3[mt][r] + bv;
            }
        }
    }
}

static inline int cdiv(int a, int b) { return (a + b - 1) / b; }

extern "C" void kernel_launch(void* const* d_in, const int* in_sizes, int n_in,
                              void* d_out, int out_size, void* d_ws, size_t ws_size,
                              hipStream_t stream) {
    const float* x0 = (const float*)d_in[0];
    const float* ea0 = (const float*)d_in[1];
    const float* enW1 = (const float*)d_in[2];
    const float* enb1 = (const float*)d_in[3];
    const float* enW2 = (const float*)d_in[4];
    const float* enb2 = (const float*)d_in[5];
    const float* enW3 = (const float*)d_in[6];
    const float* enb3 = (const float*)d_in[7];
    const float* eng = (const float*)d_in[8];
    const float* enbt = (const float*)d_in[9];
    const float* eeW1 = (const float*)d_in[10];
    const float* eeb1 = (const float*)d_in[11];
    const float* eeW2 = (const float*)d_in[12];
    const float* eeb2 = (const float*)d_in[13];
    const float* eeW3 = (const float*)d_in[14];
    const float* eeb3 = (const float*)d_in[15];
    const float* eeg = (const float*)d_in[16];
    const float* eebt = (const float*)d_in[17];
    const float* beW1 = (const float*)d_in[18];
    const float* beb1 = (const float*)d_in[19];
    const float* beW2 = (const float*)d_in[20];
    const float* beb2 = (const float*)d_in[21];
    const float* beW3 = (const float*)d_in[22];
    const float* beb3 = (const float*)d_in[23];
    const float* beg = (const float*)d_in[24];
    const float* bebt = (const float*)d_in[25];
    const float* bnW1 = (const float*)d_in[26];
    const float* bnb1 = (const float*)d_in[27];
    const float* bnW2 = (const float*)d_in[28];
    const float* bnb2 = (const float*)d_in[29];
    const float* bnW3 = (const float*)d_in[30];
    const float* bnb3 = (const float*)d_in[31];
    const float* bng = (const float*)d_in[32];
    const float* bnbt = (const float*)d_in[33];
    const float* dW1 = (const float*)d_in[34];
    const float* db1 = (const float*)d_in[35];
    const float* dW2 = (const float*)d_in[36];
    const float* db2 = (const float*)d_in[37];
    const float* dW3 = (const float*)d_in[38];
    const float* db3 = (const float*)d_in[39];
    const int* ei = (const int*)d_in[40];
    const int* senders = ei;
    const int* receivers = ei + EE;

    // ---- workspace layout (all 16B-aligned)
    char* p = (char*)d_ws;
    float* xl = (float*)p;                     p += (size_t)NN * 128 * 4;
    float* el = (float*)p;                     p += (size_t)EE * 128 * 4;
    unsigned short* xb = (unsigned short*)p;   p += (size_t)NN * 128 * 2;
    unsigned short* enew = (unsigned short*)p; p += (size_t)EE * 128 * 2;
    unsigned short* ew1t = (unsigned short*)p; p += (size_t)LL * 128 * 384 * 2;
    unsigned short* ew2t = (unsigned short*)p; p += (size_t)LL * 128 * 128 * 2;
    unsigned short* ew3t = (unsigned short*)p; p += (size_t)LL * 128 * 128 * 2;
    unsigned short* nw1t = (unsigned short*)p; p += (size_t)LL * 128 * 192 * 2;
    unsigned short* nw2t = (unsigned short*)p; p += (size_t)LL * 128 * 128 * 2;
    unsigned short* nw3t = (unsigned short*)p; p += (size_t)LL * 128 * 128 * 2;
    unsigned short* enw1p = (unsigned short*)p; p += (size_t)128 * 32 * 2;
    unsigned short* enw2t = (unsigned short*)p; p += (size_t)128 * 128 * 2;
    unsigned short* enw3t = (unsigned short*)p; p += (size_t)128 * 128 * 2;
    unsigned short* eew1p = (unsigned short*)p; p += (size_t)128 * 32 * 2;
    unsigned short* eew2t = (unsigned short*)p; p += (size_t)128 * 128 * 2;
    unsigned short* eew3t = (unsigned short*)p; p += (size_t)128 * 128 * 2;
    unsigned short* dw1t = (unsigned short*)p;  p += (size_t)128 * 128 * 2;
    unsigned short* dw2t = (unsigned short*)p;  p += (size_t)128 * 128 * 2;
    unsigned short* dw3p = (unsigned short*)p;  p += (size_t)16 * 128 * 2;
    int* cnt = (int*)p;                        p += (size_t)2 * NN * 4;   // cntR | cntS
    int* ctr = (int*)p;                        p += 16;                   // 2 counters
    int* cur = (int*)p;                        p += (size_t)2 * NN * 4;   // curR | curS
    int* offR = (int*)p;                       p += (size_t)(NN + 4) * 4;
    int* offS = (int*)p;                       p += (size_t)(NN + 4) * 4;
    int* iperm = (int*)p;                      p += (size_t)EE * 4;
    int* sendP = (int*)p;                      p += (size_t)EE * 4;
    int* recvP = (int*)p;                      p += (size_t)EE * 4;
    int* csrS = (int*)p;                       p += (size_t)EE * 4;
    int* cntR = cnt, *cntS = cnt + NN;
    int* curR = cur, *curS = cur + NN;

    dim3 blk(256);
    // ---- weight convert+transpose (per launch)
    {
        int tot;
        tot = LL * 128 * 384;
        wt_t_kernel<<<cdiv(tot, 256), blk, 0, stream>>>(beW1, ew1t, 384, 128, 384, 128, tot);
        tot = LL * 128 * 128;
        wt_t_kernel<<<cdiv(tot, 256), blk, 0, stream>>>(beW2, ew2t, 128, 128, 128, 128, tot);
        wt_t_kernel<<<cdiv(tot, 256), blk, 0, stream>>>(beW3, ew3t, 128, 128, 128, 128, tot);
        wt_t_kernel<<<cdiv(tot, 256), blk, 0, stream>>>(bnW2, nw2t, 128, 128, 128, 128, tot);
        wt_t_kernel<<<cdiv(tot, 256), blk, 0, stream>>>(bnW3, nw3t, 128, 128, 128, 128, tot);
        tot = LL * 128 * 192;
        wt_t_kernel<<<cdiv(tot, 256), blk, 0, stream>>>(bnW1, nw1t, 192, 128, 192, 128, tot);
        tot = 128 * 32;
        wt_t_kernel<<<cdiv(tot, 256), blk, 0, stream>>>(enW1, enw1p, 16, 128, 32, 128, tot);
        wt_t_kernel<<<cdiv(tot, 256), blk, 0, stream>>>(eeW1, eew1p, 16, 128, 32, 128, tot);
        tot = 128 * 128;
        wt_t_kernel<<<cdiv(tot, 256), blk, 0, stream>>>(enW2, enw2t, 128, 128, 128, 128, tot);
        wt_t_kernel<<<cdiv(tot, 256), blk, 0, stream>>>(enW3, enw3t, 128, 128, 128, 128, tot);
        wt_t_kernel<<<cdiv(tot, 256), blk, 0, stream>>>(eeW2, eew2t, 128, 128, 128, 128, tot);
        wt_t_kernel<<<cdiv(tot, 256), blk, 0, stream>>>(eeW3, eew3t, 128, 128, 128, 128, tot);
        wt_t_kernel<<<cdiv(tot, 256), blk, 0, stream>>>(dW1, dw1t, 128, 128, 128, 128, tot);
        wt_t_kernel<<<cdiv(tot, 256), blk, 0, stream>>>(dW2, dw2t, 128, 128, 128, 128, tot);
        tot = 16 * 128;
        wt_t_kernel<<<cdiv(tot, 256), blk, 0, stream>>>(dW3, dw3p, 128, 3, 128, 16, tot);
    }
    // ---- CSR build + receiver-sorted edge permutation (once per launch)
    hipMemsetAsync(cnt, 0, (size_t)2 * NN * 4 + 16, stream);
    hist_kernel<<<cdiv(EE, 256), blk, 0, stream>>>(senders, receivers, cntR, cntS);
    alloc_kernel<<<cdiv(NN, 256), blk, 0, stream>>>(cntR, cntS, offR, offS, curR, curS, ctr);
    fill_kernel<<<cdiv(EE, 256), blk, 0, stream>>>(senders, receivers, curR, curS,
                                                   iperm, sendP, recvP, csrS);

    // ---- encoders (MFMA); edge encoder writes el in receiver-sorted order
    enc_mfma_kernel<<<cdiv(NN, 128), blk, 0, stream>>>(x0, (const int*)nullptr,
                                                       enw1p, enb1, enw2t, enb2,
                                                       enw3t, enb3, eng, enbt, xl, xb, NN);
    enc_mfma_kernel<<<cdiv(EE, 128), blk, 0, stream>>>(ea0, iperm,
                                                       eew1p, eeb1, eew2t, eeb2,
                                                       eew3t, eeb3, eeg, eebt, el,
                                                       (unsigned short*)nullptr, EE);

    // ---- 15 message-passing layers
    for (int l = 0; l < LL; ++l) {
        const unsigned short* w1 = ew1t + (size_t)l * 128 * 384;
        const unsigned short* w2 = ew2t + (size_t)l * 128 * 128;
        const unsigned short* w3 = ew3t + (size_t)l * 128 * 128;
        const float* eb1 = beb1 + (size_t)l * 128;
        const float* eb2 = beb2 + (size_t)l * 128;
        const float* eb3 = beb3 + (size_t)l * 128;
        const float* eg = beg + (size_t)l * 128;
        const float* ebt = bebt + (size_t)l * 128;
        if (l < LL - 1)
            edge_mfma_kernel<true><<<cdiv(EE, 192), blk, 0, stream>>>(
                xb, el, enew, sendP, recvP, w1, eb1, w2, eb2, w3, eb3, eg, ebt);
        else
            edge_mfma_kernel<false><<<cdiv(EE, 192), blk, 0, stream>>>(
                xb, el, enew, sendP, recvP, w1, eb1, w2, eb2, w3, eb3, eg, ebt);
        const unsigned short* nw1 = nw1t + (size_t)l * 128 * 192;
        const unsigned short* nw2 = nw2t + (size_t)l * 128 * 128;
        const unsigned short* nw3 = nw3t + (size_t)l * 128 * 128;
        const float* nb1 = bnb1 + (size_t)l * 128;
        const float* nb2 = bnb2 + (size_t)l * 128;
        const float* nb3 = bnb3 + (size_t)l * 128;
        const float* ng = bng + (size_t)l * 128;
        const float* nbt = bnbt + (size_t)l * 128;
        if (l < LL - 1)
            node_mfma_kernel<true><<<cdiv(NN, 64), blk, 0, stream>>>(
                xl, xb, enew, offR, cntR, offS, cntS, csrS,
                nw1, nb1, nw2, nb2, nw3, nb3, ng, nbt);
        else
            node_mfma_kernel<false><<<cdiv(NN, 64), blk, 0, stream>>>(
                xl, xb, enew, offR, cntR, offS, cntS, csrS,
                nw1, nb1, nw2, nb2, nw3, nb3, ng, nbt);
    }
    // ---- decoder (MFMA)
    dec_mfma_kernel<<<cdiv(NN, 128), blk, 0, stream>>>(xb, dw1t, db1, dw2t, db2,
                                                       dw3p, db3, (float*)d_out, NN);
}

// Round 14
// 3333.099 us; speedup vs baseline: 1.0673x; 1.0673x over previous
//
#include <hip/hip_runtime.h>
#include <math.h>

// Problem constants (match reference setup_inputs)
#define NN 50000
#define EE 150000
#define LL 15

typedef __attribute__((ext_vector_type(8))) short short8;
typedef __attribute__((ext_vector_type(4))) float f32x4;
typedef __attribute__((ext_vector_type(2))) float f32x2;

// Paired exact-GELU via A&S 7.1.25 erf (|err| <= 2.5e-5 — ~100x below bf16 quantum).
static __device__ __forceinline__ void gelu2(float x0, float x1, float& o0, float& o1) {
    f32x2 ax = {fabsf(x0), fabsf(x1)};
    f32x2 z = ax * 0.70710678118654752440f;
    float t0 = __builtin_amdgcn_rcpf(fmaf(0.47047f, z[0], 1.0f));
    float t1 = __builtin_amdgcn_rcpf(fmaf(0.47047f, z[1], 1.0f));
    f32x2 t = {t0, t1};
    f32x2 poly = t * 0.7478556f + (f32x2)(-0.0958798f);
    poly = poly * t + (f32x2)0.3480242f;
    poly = poly * t;
    f32x2 nz2 = -z * z;
    f32x2 ex = {__expf(nz2[0]), __expf(nz2[1])};
    f32x2 erf = (f32x2)1.0f - poly * ex;
    float e0 = copysignf(erf[0], x0);
    float e1 = copysignf(erf[1], x1);
    o0 = 0.5f * x0 * (1.0f + e0);
    o1 = 0.5f * x1 * (1.0f + e1);
}

static __device__ __forceinline__ unsigned short bf16_of(float f) {
    union { float f; unsigned u; } v;
    v.f = f;
    unsigned r = (v.u + 0x7fffu + ((v.u >> 16) & 1u)) >> 16;  // RNE
    return (unsigned short)r;
}

static __device__ __forceinline__ float f_of_bf16(unsigned short u) {
    union { unsigned u; float f; } v;
    v.u = ((unsigned)u) << 16;
    return v.f;
}

// XCD-aware swizzle: consecutive logical blocks land on the SAME XCD (dispatch
// round-robins blockIdx across 8 XCDs). Grid must be a multiple of 8.
static __device__ __forceinline__ int xcd_logical_block() {
    return (blockIdx.x & 7) * ((int)gridDim.x >> 3) + ((int)blockIdx.x >> 3);
}

// ---------------- weight transpose+convert+pad:
// in [C][K][N] fp32 -> out [C][Npad][Kpad] bf16 (zero-padded)
__global__ __launch_bounds__(256) void wt_t_kernel(const float* __restrict__ in,
                                                   unsigned short* __restrict__ out,
                                                   int K, int N, int Kpad, int Npad, int total) {
    int i = blockIdx.x * 256 + threadIdx.x;
    if (i >= total) return;
    int k = i % Kpad;
    int r = i / Kpad;
    int n = r % Npad;
    int c = r / Npad;
    out[i] = (k < K && n < N) ? bf16_of(in[((size_t)c * K + k) * N + n]) : (unsigned short)0;
}

// ---------------- CSR build: histogram
__global__ __launch_bounds__(256) void hist_kernel(const int* __restrict__ senders,
                                                   const int* __restrict__ receivers,
                                                   int* __restrict__ cntR, int* __restrict__ cntS) {
    int i = blockIdx.x * 256 + threadIdx.x;
    if (i >= EE) return;
    atomicAdd(&cntR[receivers[i]], 1);
    atomicAdd(&cntS[senders[i]], 1);
}

// ---------------- CSR build: bucket allocation (order-free; wave scan + 1 atomic/wave)
__global__ __launch_bounds__(256) void alloc_kernel(const int* __restrict__ cntR,
                                                    const int* __restrict__ cntS,
                                                    int* __restrict__ offR, int* __restrict__ offS,
                                                    int* __restrict__ curR, int* __restrict__ curS,
                                                    int* __restrict__ ctr) {
    int i = blockIdx.x * 256 + threadIdx.x;
    int lane = threadIdx.x & 63;
    int cR = (i < NN) ? cntR[i] : 0;
    int cS = (i < NN) ? cntS[i] : 0;
    int sR = cR, sS = cS;
#pragma unroll
    for (int d = 1; d < 64; d <<= 1) {
        int tR = __shfl_up(sR, d, 64);
        int tS = __shfl_up(sS, d, 64);
        if (lane >= d) { sR += tR; sS += tS; }
    }
    int baseR = 0, baseS = 0;
    if (lane == 63) {
        baseR = atomicAdd(&ctr[0], sR);
        baseS = atomicAdd(&ctr[1], sS);
    }
    baseR = __shfl(baseR, 63, 64);
    baseS = __shfl(baseS, 63, 64);
    if (i < NN) {
        int oR = baseR + sR - cR;
        offR[i] = oR; curR[i] = oR;
        int oS = baseS + sS - cS;
        offS[i] = oS; curS[i] = oS;
    }
}

// ---------------- CSR build: fill — receiver-sorted edge permutation.
__global__ __launch_bounds__(256) void fill_kernel(const int* __restrict__ senders,
                                                   const int* __restrict__ receivers,
                                                   int* __restrict__ curR, int* __restrict__ curS,
                                                   int* __restrict__ iperm,
                                                   int* __restrict__ sendP, int* __restrict__ recvP,
                                                   int* __restrict__ csrS) {
    int i = blockIdx.x * 256 + threadIdx.x;
    if (i >= EE) return;
    int snd = senders[i], rcv = receivers[i];
    int pr = atomicAdd(&curR[rcv], 1);
    iperm[pr] = i;
    sendP[pr] = snd;
    recvP[pr] = rcv;
    int ps = atomicAdd(&curS[snd], 1);
    csrS[ps] = pr;
}

// ======== shared MFMA helpers ========
template <int MT>
static __device__ __forceinline__ void mlp_from_h(const unsigned short* hb,
                                                  const unsigned short* __restrict__ Wt,
                                                  f32x4 acc[][8], int m, int q) {
#pragma unroll
    for (int c = 0; c < 4; ++c) {
        short8 af[MT];
#pragma unroll
        for (int mt = 0; mt < MT; ++mt)
            af[mt] = *(const short8*)(hb + (mt * 16 + m) * 136 + c * 32 + q * 8);
#pragma unroll
        for (int nt = 0; nt < 8; ++nt) {
            short8 bf = *(const short8*)(Wt + ((size_t)(nt * 16 + m)) * 128 + c * 32 + q * 8);
#pragma unroll
            for (int mt = 0; mt < MT; ++mt)
                acc[mt][nt] = __builtin_amdgcn_mfma_f32_16x16x32_bf16(af[mt], bf, acc[mt][nt], 0, 0, 0);
        }
    }
}

template <int MT>
static __device__ __forceinline__ void gelu_to_h(f32x4 acc[][8], const float* __restrict__ b,
                                                 unsigned short* hb, int m, int q) {
#pragma unroll
    for (int nt = 0; nt < 8; ++nt) {
        float bv = b[nt * 16 + m];
#pragma unroll
        for (int mt = 0; mt < MT; ++mt) {
#pragma unroll
            for (int r = 0; r < 4; r += 2) {
                float g0, g1;
                gelu2(acc[mt][nt][r] + bv, acc[mt][nt][r + 1] + bv, g0, g1);
                hb[(mt * 16 + q * 4 + r) * 136 + nt * 16 + m] = bf16_of(g0);
                hb[(mt * 16 + q * 4 + r + 1) * 136 + nt * 16 + m] = bf16_of(g1);
            }
            acc[mt][nt] = (f32x4)0.f;
        }
    }
}

// ================= MFMA edge block: 192 edges/block, 4 waves x 48 rows (3 m-tiles)
// (256,4) pins VGPR budget at 128 (R11/R12: natural 120-124, no spills).
// Grid padded to x8 for the XCD swizzle; OOB blocks are store-guarded no-ops.
template <bool WRITE_EL>
__global__ __launch_bounds__(256, 4) void edge_mfma_kernel(
    const unsigned short* __restrict__ xb, float* __restrict__ el,
    unsigned short* __restrict__ enew,
    const int* __restrict__ sendP, const int* __restrict__ recvP,
    const unsigned short* __restrict__ W1t, const float* __restrict__ b1,
    const unsigned short* __restrict__ W2t, const float* __restrict__ b2,
    const unsigned short* __restrict__ W3t, const float* __restrict__ b3,
    const float* __restrict__ g, const float* __restrict__ beta) {
    __shared__ __align__(16) unsigned short h[4][48][136];  // 52.2 KB
    int t = threadIdx.x;
    int w = t >> 6;
    int l = t & 63;
    int m = l & 15;
    int q = l >> 4;
    int lb = xcd_logical_block();
    int rbase = lb * 192 + w * 48;

    int arow[3], as[3], ar[3];
#pragma unroll
    for (int mt = 0; mt < 3; ++mt) {
        int rw = rbase + mt * 16 + m;
        if (rw >= EE) rw = EE - 1;
        arow[mt] = rw;
        as[mt] = sendP[rw];
        ar[mt] = recvP[rw];
    }

    f32x4 acc[3][8];
#pragma unroll
    for (int mt = 0; mt < 3; ++mt)
#pragma unroll
        for (int nt = 0; nt < 8; ++nt) acc[mt][nt] = (f32x4)0.f;

    // ---- MLP1: K=384 (12 chunks): 0..3 x[sender], 4..7 x[receiver], 8..11 e (fp32->bf16)
#pragma unroll
    for (int c = 0; c < 12; ++c) {
        short8 af[3];
#pragma unroll
        for (int mt = 0; mt < 3; ++mt) {
            if (c < 4) {
                af[mt] = *(const short8*)(xb + (size_t)as[mt] * 128 + c * 32 + q * 8);
            } else if (c < 8) {
                af[mt] = *(const short8*)(xb + (size_t)ar[mt] * 128 + (c - 4) * 32 + q * 8);
            } else {
                const float* fp = el + (size_t)arow[mt] * 128 + (c - 8) * 32 + q * 8;
                float4 f0 = *(const float4*)fp;
                float4 f1 = *(const float4*)(fp + 4);
                short8 a;
                a[0] = (short)bf16_of(f0.x); a[1] = (short)bf16_of(f0.y);
                a[2] = (short)bf16_of(f0.z); a[3] = (short)bf16_of(f0.w);
                a[4] = (short)bf16_of(f1.x); a[5] = (short)bf16_of(f1.y);
                a[6] = (short)bf16_of(f1.z); a[7] = (short)bf16_of(f1.w);
                af[mt] = a;
            }
        }
#pragma unroll
        for (int nt = 0; nt < 8; ++nt) {
            short8 bf = *(const short8*)(W1t + ((size_t)(nt * 16 + m)) * 384 + c * 32 + q * 8);
#pragma unroll
            for (int mt = 0; mt < 3; ++mt)
                acc[mt][nt] = __builtin_amdgcn_mfma_f32_16x16x32_bf16(af[mt], bf, acc[mt][nt], 0, 0, 0);
        }
    }
    gelu_to_h<3>(acc, b1, &h[w][0][0], m, q);
    mlp_from_h<3>(&h[w][0][0], W2t, acc, m, q);
    gelu_to_h<3>(acc, b2, &h[w][0][0], m, q);
    mlp_from_h<3>(&h[w][0][0], W3t, acc, m, q);

    // ---- epilogue: bias, LN over 128, residual into el (compile-time-skipped last layer)
    float gv[8], btv[8];
#pragma unroll
    for (int nt = 0; nt < 8; ++nt) { gv[nt] = g[nt * 16 + m]; btv[nt] = beta[nt * 16 + m]; }
#pragma unroll
    for (int mt = 0; mt < 3; ++mt) {
        float s[4] = {0.f, 0.f, 0.f, 0.f}, ss[4] = {0.f, 0.f, 0.f, 0.f};
#pragma unroll
        for (int nt = 0; nt < 8; ++nt) {
            float bv = b3[nt * 16 + m];
#pragma unroll
            for (int r = 0; r < 4; ++r) {
                float v = acc[mt][nt][r] + bv;
                acc[mt][nt][r] = v;
                s[r] += v;
                ss[r] += v * v;
            }
        }
#pragma unroll
        for (int r = 0; r < 4; ++r) {
#pragma unroll
            for (int msk = 1; msk < 16; msk <<= 1) {
                s[r] += __shfl_xor(s[r], msk, 64);
                ss[r] += __shfl_xor(ss[r], msk, 64);
            }
        }
#pragma unroll
        for (int r = 0; r < 4; ++r) {
            int row = rbase + mt * 16 + q * 4 + r;
            if (row < EE) {
                float mean = s[r] * (1.0f / 128.0f);
                float var = ss[r] * (1.0f / 128.0f) - mean * mean;
                float rstd = rsqrtf(var + 1e-5f);
#pragma unroll
                for (int nt = 0; nt < 8; ++nt) {
                    int col = nt * 16 + m;
                    float v = (acc[mt][nt][r] - mean) * rstd * gv[nt] + btv[nt];
                    size_t off = (size_t)row * 128 + col;
                    if (WRITE_EL) el[off] = el[off] + v;
                    enew[off] = bf16_of(v);
                }
            }
        }
    }
}

// ================= MFMA node block: 128 nodes/block, 4 waves x 32 rows (2 m-tiles)
// [R13 post-mortem: mt=1 halved MFMA-per-B-load and regressed; mt=2 is optimal.]
template <bool WRITE_XL>
__global__ __launch_bounds__(256) void node_mfma_kernel(
    float* __restrict__ xl, unsigned short* __restrict__ xb,
    const unsigned short* __restrict__ enew,
    const int* __restrict__ offR, const int* __restrict__ cntR,
    const int* __restrict__ offS, const int* __restrict__ cntS, const int* __restrict__ csrS,
    const unsigned short* __restrict__ W1t, const float* __restrict__ b1,
    const unsigned short* __restrict__ W2t, const float* __restrict__ b2,
    const unsigned short* __restrict__ W3t, const float* __restrict__ b3,
    const float* __restrict__ g, const float* __restrict__ beta) {
    __shared__ __align__(16) unsigned short h[4][32][136];
    int t = threadIdx.x;
    int w = t >> 6;
    int l = t & 63;
    int m = l & 15;
    int q = l >> 4;
    int lb = xcd_logical_block();
    int rbase = lb * 128 + w * 32;

    // ---- aggregation prologue (no atomics; R-half contiguous, unroll-2)
    float aggv[2][16];
#pragma unroll
    for (int mt = 0; mt < 2; ++mt)
#pragma unroll
        for (int j = 0; j < 16; ++j) aggv[mt][j] = 0.f;
#pragma unroll
    for (int mt = 0; mt < 2; ++mt) {
        int rw = rbase + mt * 16 + m;
        if (rw < NN) {
            // receiver half (cols 0..63), contiguous rows
            {
                int b0 = offR[rw], bn = b0 + cntR[rw];
                int p = b0;
                for (; p + 2 <= bn; p += 2) {
                    const unsigned short* bp0 = enew + (size_t)p * 128;
                    short8 a0 = *(const short8*)(bp0 + q * 8);
                    short8 a1 = *(const short8*)(bp0 + 32 + q * 8);
                    short8 c0 = *(const short8*)(bp0 + 128 + q * 8);
                    short8 c1 = *(const short8*)(bp0 + 128 + 32 + q * 8);
#pragma unroll
                    for (int j = 0; j < 8; ++j) {
                        aggv[mt][j] += f_of_bf16((unsigned short)a0[j]) + f_of_bf16((unsigned short)c0[j]);
                        aggv[mt][8 + j] += f_of_bf16((unsigned short)a1[j]) + f_of_bf16((unsigned short)c1[j]);
                    }
                }
                if (p < bn) {
                    const unsigned short* bp0 = enew + (size_t)p * 128;
                    short8 a0 = *(const short8*)(bp0 + q * 8);
                    short8 a1 = *(const short8*)(bp0 + 32 + q * 8);
#pragma unroll
                    for (int j = 0; j < 8; ++j) {
                        aggv[mt][j] += f_of_bf16((unsigned short)a0[j]);
                        aggv[mt][8 + j] += f_of_bf16((unsigned short)a1[j]);
                    }
                }
            }
            // sender half (cols 64..127), gather via csrS (permuted ids)
            {
                int b0 = offS[rw], bn = b0 + cntS[rw];
                int p = b0;
                for (; p + 2 <= bn; p += 2) {
                    int e0 = csrS[p], e1 = csrS[p + 1];
                    const unsigned short* bp0 = enew + (size_t)e0 * 128 + 64;
                    const unsigned short* bp1 = enew + (size_t)e1 * 128 + 64;
                    short8 a0 = *(const short8*)(bp0 + q * 8);
                    short8 a1 = *(const short8*)(bp0 + 32 + q * 8);
                    short8 c0 = *(const short8*)(bp1 + q * 8);
                    short8 c1 = *(const short8*)(bp1 + 32 + q * 8);
#pragma unroll
                    for (int j = 0; j < 8; ++j) {
                        aggv[mt][j] += f_of_bf16((unsigned short)a0[j]) + f_of_bf16((unsigned short)c0[j]);
                        aggv[mt][8 + j] += f_of_bf16((unsigned short)a1[j]) + f_of_bf16((unsigned short)c1[j]);
                    }
                }
                if (p < bn) {
                    int e0 = csrS[p];
                    const unsigned short* bp0 = enew + (size_t)e0 * 128 + 64;
                    short8 a0 = *(const short8*)(bp0 + q * 8);
                    short8 a1 = *(const short8*)(bp0 + 32 + q * 8);
#pragma unroll
                    for (int j = 0; j < 8; ++j) {
                        aggv[mt][j] += f_of_bf16((unsigned short)a0[j]);
                        aggv[mt][8 + j] += f_of_bf16((unsigned short)a1[j]);
                    }
                }
            }
        }
    }

    int arow[2];
#pragma unroll
    for (int mt = 0; mt < 2; ++mt) {
        int rw = rbase + mt * 16 + m;
        arow[mt] = (rw < NN) ? rw : (NN - 1);
    }

    f32x4 acc[2][8];
#pragma unroll
    for (int mt = 0; mt < 2; ++mt)
#pragma unroll
        for (int nt = 0; nt < 8; ++nt) acc[mt][nt] = (f32x4)0.f;

    // ---- MLP1: K=192 (6 chunks): 0..3 xb, 4..5 agg (registers)
#pragma unroll
    for (int c = 0; c < 6; ++c) {
        short8 af[2];
#pragma unroll
        for (int mt = 0; mt < 2; ++mt) {
            if (c < 4) {
                af[mt] = *(const short8*)(xb + (size_t)arow[mt] * 128 + c * 32 + q * 8);
            } else {
                short8 a;
#pragma unroll
                for (int j = 0; j < 8; ++j)
                    a[j] = (short)bf16_of(aggv[mt][(c - 4) * 8 + j]);
                af[mt] = a;
            }
        }
#pragma unroll
        for (int nt = 0; nt < 8; ++nt) {
            short8 bf = *(const short8*)(W1t + ((size_t)(nt * 16 + m)) * 192 + c * 32 + q * 8);
#pragma unroll
            for (int mt = 0; mt < 2; ++mt)
                acc[mt][nt] = __builtin_amdgcn_mfma_f32_16x16x32_bf16(af[mt], bf, acc[mt][nt], 0, 0, 0);
        }
    }
    gelu_to_h<2>(acc, b1, &h[w][0][0], m, q);
    mlp_from_h<2>(&h[w][0][0], W2t, acc, m, q);
    gelu_to_h<2>(acc, b2, &h[w][0][0], m, q);
    mlp_from_h<2>(&h[w][0][0], W3t, acc, m, q);

    // ---- epilogue: LN, residual into xl (compile-time-skipped last layer), xb mirror
    float gv[8], btv[8];
#pragma unroll
    for (int nt = 0; nt < 8; ++nt) { gv[nt] = g[nt * 16 + m]; btv[nt] = beta[nt * 16 + m]; }
#pragma unroll
    for (int mt = 0; mt < 2; ++mt) {
        float s[4] = {0.f, 0.f, 0.f, 0.f}, ss[4] = {0.f, 0.f, 0.f, 0.f};
#pragma unroll
        for (int nt = 0; nt < 8; ++nt) {
            float bv = b3[nt * 16 + m];
#pragma unroll
            for (int r = 0; r < 4; ++r) {
                float v = acc[mt][nt][r] + bv;
                acc[mt][nt][r] = v;
                s[r] += v;
                ss[r] += v * v;
            }
        }
#pragma unroll
        for (int r = 0; r < 4; ++r) {
#pragma unroll
            for (int msk = 1; msk < 16; msk <<= 1) {
                s[r] += __shfl_xor(s[r], msk, 64);
                ss[r] += __shfl_xor(ss[r], msk, 64);
            }
        }
#pragma unroll
        for (int r = 0; r < 4; ++r) {
            int row = rbase + mt * 16 + q * 4 + r;
            if (row < NN) {
                float mean = s[r] * (1.0f / 128.0f);
                float var = ss[r] * (1.0f / 128.0f) - mean * mean;
                float rstd = rsqrtf(var + 1e-5f);
#pragma unroll
                for (int nt = 0; nt < 8; ++nt) {
                    int col = nt * 16 + m;
                    float v = (acc[mt][nt][r] - mean) * rstd * gv[nt] + btv[nt];
                    size_t off = (size_t)row * 128 + col;
                    float res = xl[off] + v;
                    if (WRITE_XL) xl[off] = res;
                    xb[off] = bf16_of(res);
                }
            }
        }
    }
}

// ================= MFMA encoder: [rows,16] -> MLP(16->128->128->128) -> LN
__global__ __launch_bounds__(256) void enc_mfma_kernel(
    const float* __restrict__ in, const int* __restrict__ gather,
    const unsigned short* __restrict__ W1p, const float* __restrict__ b1,
    const unsigned short* __restrict__ W2t, const float* __restrict__ b2,
    const unsigned short* __restrict__ W3t, const float* __restrict__ b3,
    const float* __restrict__ g, const float* __restrict__ beta,
    float* __restrict__ outF, unsigned short* __restrict__ outB, int nrows) {
    __shared__ __align__(16) unsigned short h[4][32][136];
    int t = threadIdx.x;
    int w = t >> 6;
    int l = t & 63;
    int m = l & 15;
    int q = l >> 4;
    int rbase = blockIdx.x * 128 + w * 32;

    int arow[2];
#pragma unroll
    for (int mt = 0; mt < 2; ++mt) {
        int rw = rbase + mt * 16 + m;
        rw = (rw < nrows) ? rw : (nrows - 1);
        arow[mt] = gather ? gather[rw] : rw;
    }

    f32x4 acc[2][8];
#pragma unroll
    for (int mt = 0; mt < 2; ++mt)
#pragma unroll
        for (int nt = 0; nt < 8; ++nt) acc[mt][nt] = (f32x4)0.f;

    // ---- MLP1: single K=32 chunk (k>=16 zero)
    {
        short8 af[2];
#pragma unroll
        for (int mt = 0; mt < 2; ++mt) {
            short8 a = (short8)0;
            if (q < 2) {
                const float* fp = in + (size_t)arow[mt] * 16 + q * 8;
                float4 f0 = *(const float4*)fp;
                float4 f1 = *(const float4*)(fp + 4);
                a[0] = (short)bf16_of(f0.x); a[1] = (short)bf16_of(f0.y);
                a[2] = (short)bf16_of(f0.z); a[3] = (short)bf16_of(f0.w);
                a[4] = (short)bf16_of(f1.x); a[5] = (short)bf16_of(f1.y);
                a[6] = (short)bf16_of(f1.z); a[7] = (short)bf16_of(f1.w);
            }
            af[mt] = a;
        }
#pragma unroll
        for (int nt = 0; nt < 8; ++nt) {
            short8 bf = *(const short8*)(W1p + ((size_t)(nt * 16 + m)) * 32 + q * 8);
#pragma unroll
            for (int mt = 0; mt < 2; ++mt)
                acc[mt][nt] = __builtin_amdgcn_mfma_f32_16x16x32_bf16(af[mt], bf, acc[mt][nt], 0, 0, 0);
        }
    }
    gelu_to_h<2>(acc, b1, &h[w][0][0], m, q);
    mlp_from_h<2>(&h[w][0][0], W2t, acc, m, q);
    gelu_to_h<2>(acc, b2, &h[w][0][0], m, q);
    mlp_from_h<2>(&h[w][0][0], W3t, acc, m, q);

    float gv[8], btv[8];
#pragma unroll
    for (int nt = 0; nt < 8; ++nt) { gv[nt] = g[nt * 16 + m]; btv[nt] = beta[nt * 16 + m]; }
#pragma unroll
    for (int mt = 0; mt < 2; ++mt) {
        float s[4] = {0.f, 0.f, 0.f, 0.f}, ss[4] = {0.f, 0.f, 0.f, 0.f};
#pragma unroll
        for (int nt = 0; nt < 8; ++nt) {
            float bv = b3[nt * 16 + m];
#pragma unroll
            for (int r = 0; r < 4; ++r) {
                float v = acc[mt][nt][r] + bv;
                acc[mt][nt][r] = v;
                s[r] += v;
                ss[r] += v * v;
            }
        }
#pragma unroll
        for (int r = 0; r < 4; ++r) {
#pragma unroll
            for (int msk = 1; msk < 16; msk <<= 1) {
                s[r] += __shfl_xor(s[r], msk, 64);
                ss[r] += __shfl_xor(ss[r], msk, 64);
            }
        }
#pragma unroll
        for (int r = 0; r < 4; ++r) {
            int row = rbase + mt * 16 + q * 4 + r;
            if (row < nrows) {
                float mean = s[r] * (1.0f / 128.0f);
                float var = ss[r] * (1.0f / 128.0f) - mean * mean;
                float rstd = rsqrtf(var + 1e-5f);
#pragma unroll
                for (int nt = 0; nt < 8; ++nt) {
                    int col = nt * 16 + m;
                    float v = (acc[mt][nt][r] - mean) * rstd * gv[nt] + btv[nt];
                    size_t off = (size_t)row * 128 + col;
                    outF[off] = v;
                    if (outB) outB[off] = bf16_of(v);
                }
            }
        }
    }
}

// ================= MFMA decoder: xb -> MLP(128->128->128->3)
__global__ __launch_bounds__(256) void dec_mfma_kernel(
    const unsigned short* __restrict__ xb,
    const unsigned short* __restrict__ W1t, const float* __restrict__ b1,
    const unsigned short* __restrict__ W2t, const float* __restrict__ b2,
    const unsigned short* __restrict__ W3p, const float* __restrict__ b3,
    float* __restrict__ out, int N_) {
    __shared__ __align__(16) unsigned short h[4][32][136];
    int t = threadIdx.x;
    int w = t >> 6;
    int l = t & 63;
    int m = l & 15;
    int q = l >> 4;
    int rbase = blockIdx.x * 128 + w * 32;

    int arow[2];
#pragma unroll
    for (int mt = 0; mt < 2; ++mt) {
        int rw = rbase + mt * 16 + m;
        arow[mt] = (rw < N_) ? rw : (N_ - 1);
    }

    f32x4 acc[2][8];
#pragma unroll
    for (int mt = 0; mt < 2; ++mt)
#pragma unroll
        for (int nt = 0; nt < 8; ++nt) acc[mt][nt] = (f32x4)0.f;

    // ---- MLP1: K=128 from xb
#pragma unroll
    for (int c = 0; c < 4; ++c) {
        short8 af[2];
#pragma unroll
        for (int mt = 0; mt < 2; ++mt)
            af[mt] = *(const short8*)(xb + (size_t)arow[mt] * 128 + c * 32 + q * 8);
#pragma unroll
        for (int nt = 0; nt < 8; ++nt) {
            short8 bf = *(const short8*)(W1t + ((size_t)(nt * 16 + m)) * 128 + c * 32 + q * 8);
#pragma unroll
            for (int mt = 0; mt < 2; ++mt)
                acc[mt][nt] = __builtin_amdgcn_mfma_f32_16x16x32_bf16(af[mt], bf, acc[mt][nt], 0, 0, 0);
        }
    }
    gelu_to_h<2>(acc, b1, &h[w][0][0], m, q);
    mlp_from_h<2>(&h[w][0][0], W2t, acc, m, q);
    gelu_to_h<2>(acc, b2, &h[w][0][0], m, q);

    // ---- final: 128 -> 3 (one padded n-tile)
    f32x4 a3[2];
    a3[0] = (f32x4)0.f;
    a3[1] = (f32x4)0.f;
#pragma unroll
    for (int c = 0; c < 4; ++c) {
        short8 bf = *(const short8*)(W3p + ((size_t)m) * 128 + c * 32 + q * 8);
#pragma unroll
        for (int mt = 0; mt < 2; ++mt) {
            short8 af = *(const short8*)(&h[w][0][0] + (mt * 16 + m) * 136 + c * 32 + q * 8);
            a3[mt] = __builtin_amdgcn_mfma_f32_16x16x32_bf16(af, bf, a3[mt], 0, 0, 0);
        }
    }
    if (m < 3) {
        float bv = b3[m];
#pragma unroll
        for (int mt = 0; mt < 2; ++mt) {
#pragma unroll
            for (int r = 0; r < 4; ++r) {
                int row = rbase + mt * 16 + q * 4 + r;
                if (row < N_) out[(size_t)row * 3 + m] = a3[mt][r] + bv;
            }
        }
    }
}

static inline int cdiv(int a, int b) { return (a + b - 1) / b; }
static inline int pad8(int x) { return (x + 7) & ~7; }

extern "C" void kernel_launch(void* const* d_in, const int* in_sizes, int n_in,
                              void* d_out, int out_size, void* d_ws, size_t ws_size,
                              hipStream_t stream) {
    const float* x0 = (const float*)d_in[0];
    const float* ea0 = (const float*)d_in[1];
    const float* enW1 = (const float*)d_in[2];
    const float* enb1 = (const float*)d_in[3];
    const float* enW2 = (const float*)d_in[4];
    const float* enb2 = (const float*)d_in[5];
    const float* enW3 = (const float*)d_in[6];
    const float* enb3 = (const float*)d_in[7];
    const float* eng = (const float*)d_in[8];
    const float* enbt = (const float*)d_in[9];
    const float* eeW1 = (const float*)d_in[10];
    const float* eeb1 = (const float*)d_in[11];
    const float* eeW2 = (const float*)d_in[12];
    const float* eeb2 = (const float*)d_in[13];
    const float* eeW3 = (const float*)d_in[14];
    const float* eeb3 = (const float*)d_in[15];
    const float* eeg = (const float*)d_in[16];
    const float* eebt = (const float*)d_in[17];
    const float* beW1 = (const float*)d_in[18];
    const float* beb1 = (const float*)d_in[19];
    const float* beW2 = (const float*)d_in[20];
    const float* beb2 = (const float*)d_in[21];
    const float* beW3 = (const float*)d_in[22];
    const float* beb3 = (const float*)d_in[23];
    const float* beg = (const float*)d_in[24];
    const float* bebt = (const float*)d_in[25];
    const float* bnW1 = (const float*)d_in[26];
    const float* bnb1 = (const float*)d_in[27];
    const float* bnW2 = (const float*)d_in[28];
    const float* bnb2 = (const float*)d_in[29];
    const float* bnW3 = (const float*)d_in[30];
    const float* bnb3 = (const float*)d_in[31];
    const float* bng = (const float*)d_in[32];
    const float* bnbt = (const float*)d_in[33];
    const float* dW1 = (const float*)d_in[34];
    const float* db1 = (const float*)d_in[35];
    const float* dW2 = (const float*)d_in[36];
    const float* db2 = (const float*)d_in[37];
    const float* dW3 = (const float*)d_in[38];
    const float* db3 = (const float*)d_in[39];
    const int* ei = (const int*)d_in[40];
    const int* senders = ei;
    const int* receivers = ei + EE;

    // ---- workspace layout (all 16B-aligned)
    char* p = (char*)d_ws;
    float* xl = (float*)p;                     p += (size_t)NN * 128 * 4;
    float* el = (float*)p;                     p += (size_t)EE * 128 * 4;
    unsigned short* xb = (unsigned short*)p;   p += (size_t)NN * 128 * 2;
    unsigned short* enew = (unsigned short*)p; p += (size_t)EE * 128 * 2;
    unsigned short* ew1t = (unsigned short*)p; p += (size_t)LL * 128 * 384 * 2;
    unsigned short* ew2t = (unsigned short*)p; p += (size_t)LL * 128 * 128 * 2;
    unsigned short* ew3t = (unsigned short*)p; p += (size_t)LL * 128 * 128 * 2;
    unsigned short* nw1t = (unsigned short*)p; p += (size_t)LL * 128 * 192 * 2;
    unsigned short* nw2t = (unsigned short*)p; p += (size_t)LL * 128 * 128 * 2;
    unsigned short* nw3t = (unsigned short*)p; p += (size_t)LL * 128 * 128 * 2;
    unsigned short* enw1p = (unsigned short*)p; p += (size_t)128 * 32 * 2;
    unsigned short* enw2t = (unsigned short*)p; p += (size_t)128 * 128 * 2;
    unsigned short* enw3t = (unsigned short*)p; p += (size_t)128 * 128 * 2;
    unsigned short* eew1p = (unsigned short*)p; p += (size_t)128 * 32 * 2;
    unsigned short* eew2t = (unsigned short*)p; p += (size_t)128 * 128 * 2;
    unsigned short* eew3t = (unsigned short*)p; p += (size_t)128 * 128 * 2;
    unsigned short* dw1t = (unsigned short*)p;  p += (size_t)128 * 128 * 2;
    unsigned short* dw2t = (unsigned short*)p;  p += (size_t)128 * 128 * 2;
    unsigned short* dw3p = (unsigned short*)p;  p += (size_t)16 * 128 * 2;
    int* cnt = (int*)p;                        p += (size_t)2 * NN * 4;   // cntR | cntS
    int* ctr = (int*)p;                        p += 16;                   // 2 counters
    int* cur = (int*)p;                        p += (size_t)2 * NN * 4;   // curR | curS
    int* offR = (int*)p;                       p += (size_t)(NN + 4) * 4;
    int* offS = (int*)p;                       p += (size_t)(NN + 4) * 4;
    int* iperm = (int*)p;                      p += (size_t)EE * 4;
    int* sendP = (int*)p;                      p += (size_t)EE * 4;
    int* recvP = (int*)p;                      p += (size_t)EE * 4;
    int* csrS = (int*)p;                       p += (size_t)EE * 4;
    int* cntR = cnt, *cntS = cnt + NN;
    int* curR = cur, *curS = cur + NN;

    dim3 blk(256);
    // ---- weight convert+transpose (per launch)
    {
        int tot;
        tot = LL * 128 * 384;
        wt_t_kernel<<<cdiv(tot, 256), blk, 0, stream>>>(beW1, ew1t, 384, 128, 384, 128, tot);
        tot = LL * 128 * 128;
        wt_t_kernel<<<cdiv(tot, 256), blk, 0, stream>>>(beW2, ew2t, 128, 128, 128, 128, tot);
        wt_t_kernel<<<cdiv(tot, 256), blk, 0, stream>>>(beW3, ew3t, 128, 128, 128, 128, tot);
        wt_t_kernel<<<cdiv(tot, 256), blk, 0, stream>>>(bnW2, nw2t, 128, 128, 128, 128, tot);
        wt_t_kernel<<<cdiv(tot, 256), blk, 0, stream>>>(bnW3, nw3t, 128, 128, 128, 128, tot);
        tot = LL * 128 * 192;
        wt_t_kernel<<<cdiv(tot, 256), blk, 0, stream>>>(bnW1, nw1t, 192, 128, 192, 128, tot);
        tot = 128 * 32;
        wt_t_kernel<<<cdiv(tot, 256), blk, 0, stream>>>(enW1, enw1p, 16, 128, 32, 128, tot);
        wt_t_kernel<<<cdiv(tot, 256), blk, 0, stream>>>(eeW1, eew1p, 16, 128, 32, 128, tot);
        tot = 128 * 128;
        wt_t_kernel<<<cdiv(tot, 256), blk, 0, stream>>>(enW2, enw2t, 128, 128, 128, 128, tot);
        wt_t_kernel<<<cdiv(tot, 256), blk, 0, stream>>>(enW3, enw3t, 128, 128, 128, 128, tot);
        wt_t_kernel<<<cdiv(tot, 256), blk, 0, stream>>>(eeW2, eew2t, 128, 128, 128, 128, tot);
        wt_t_kernel<<<cdiv(tot, 256), blk, 0, stream>>>(eeW3, eew3t, 128, 128, 128, 128, tot);
        wt_t_kernel<<<cdiv(tot, 256), blk, 0, stream>>>(dW1, dw1t, 128, 128, 128, 128, tot);
        wt_t_kernel<<<cdiv(tot, 256), blk, 0, stream>>>(dW2, dw2t, 128, 128, 128, 128, tot);
        tot = 16 * 128;
        wt_t_kernel<<<cdiv(tot, 256), blk, 0, stream>>>(dW3, dw3p, 128, 3, 128, 16, tot);
    }
    // ---- CSR build + receiver-sorted edge permutation (once per launch)
    hipMemsetAsync(cnt, 0, (size_t)2 * NN * 4 + 16, stream);
    hist_kernel<<<cdiv(EE, 256), blk, 0, stream>>>(senders, receivers, cntR, cntS);
    alloc_kernel<<<cdiv(NN, 256), blk, 0, stream>>>(cntR, cntS, offR, offS, curR, curS, ctr);
    fill_kernel<<<cdiv(EE, 256), blk, 0, stream>>>(senders, receivers, curR, curS,
                                                   iperm, sendP, recvP, csrS);

    // ---- encoders (MFMA); edge encoder writes el in receiver-sorted order
    enc_mfma_kernel<<<cdiv(NN, 128), blk, 0, stream>>>(x0, (const int*)nullptr,
                                                       enw1p, enb1, enw2t, enb2,
                                                       enw3t, enb3, eng, enbt, xl, xb, NN);
    enc_mfma_kernel<<<cdiv(EE, 128), blk, 0, stream>>>(ea0, iperm,
                                                       eew1p, eeb1, eew2t, eeb2,
                                                       eew3t, eeb3, eeg, eebt, el,
                                                       (unsigned short*)nullptr, EE);

    // ---- 15 message-passing layers (grids padded to x8 for the XCD swizzle)
    int egrid = pad8(cdiv(EE, 192));
    int ngrid = pad8(cdiv(NN, 128));
    for (int l = 0; l < LL; ++l) {
        const unsigned short* w1 = ew1t + (size_t)l * 128 * 384;
        const unsigned short* w2 = ew2t + (size_t)l * 128 * 128;
        const unsigned short* w3 = ew3t + (size_t)l * 128 * 128;
        const float* eb1 = beb1 + (size_t)l * 128;
        const float* eb2 = beb2 + (size_t)l * 128;
        const float* eb3 = beb3 + (size_t)l * 128;
        const float* eg = beg + (size_t)l * 128;
        const float* ebt = bebt + (size_t)l * 128;
        if (l < LL - 1)
            edge_mfma_kernel<true><<<egrid, blk, 0, stream>>>(
                xb, el, enew, sendP, recvP, w1, eb1, w2, eb2, w3, eb3, eg, ebt);
        else
            edge_mfma_kernel<false><<<egrid, blk, 0, stream>>>(
                xb, el, enew, sendP, recvP, w1, eb1, w2, eb2, w3, eb3, eg, ebt);
        const unsigned short* nw1 = nw1t + (size_t)l * 128 * 192;
        const unsigned short* nw2 = nw2t + (size_t)l * 128 * 128;
        const unsigned short* nw3 = nw3t + (size_t)l * 128 * 128;
        const float* nb1 = bnb1 + (size_t)l * 128;
        const float* nb2 = bnb2 + (size_t)l * 128;
        const float* nb3 = bnb3 + (size_t)l * 128;
        const float* ng = bng + (size_t)l * 128;
        const float* nbt = bnbt + (size_t)l * 128;
        if (l < LL - 1)
            node_mfma_kernel<true><<<ngrid, blk, 0, stream>>>(
                xl, xb, enew, offR, cntR, offS, cntS, csrS,
                nw1, nb1, nw2, nb2, nw3, nb3, ng, nbt);
        else
            node_mfma_kernel<false><<<ngrid, blk, 0, stream>>>(
                xl, xb, enew, offR, cntR, offS, cntS, csrS,
                nw1, nb1, nw2, nb2, nw3, nb3, ng, nbt);
    }
    // ---- decoder (MFMA)
    dec_mfma_kernel<<<cdiv(NN, 128), blk, 0, stream>>>(xb, dw1t, db1, dw2t, db2,
                                                       dw3p, db3, (float*)d_out, NN);
}